// Round 5
// baseline (1078.611 us; speedup 1.0000x reference)
//
#include <hip/hip_runtime.h>
#include <hip/hip_bf16.h>
#include <math.h>

#define Bsz 1024
#define Nn  11
#define Ff  512
#define Zi  10
#define G3  1536

#define PLW 8224   // W plane stride bytes (512 g * 16B + 32 pad) -> bank-offset 8
#define PLA 1056   // A plane stride bytes (64 rows * 16B + 32 pad)
#define PGW 4128   // gates W plane stride (256 g * 16B + 32 pad)

typedef __attribute__((ext_vector_type(8))) short bfrag;
typedef __attribute__((ext_vector_type(16))) float f32x16;

__device__ __forceinline__ unsigned f2bf(float f) {
    __hip_bfloat16 h = __float2bfloat16(f);
    return (unsigned)*reinterpret_cast<unsigned short*>(&h);
}
__device__ __forceinline__ uint4 pack8(float v0, float v1, float v2, float v3,
                                       float v4, float v5, float v6, float v7) {
    uint4 pk;
    pk.x = f2bf(v0) | (f2bf(v1) << 16);
    pk.y = f2bf(v2) | (f2bf(v3) << 16);
    pk.z = f2bf(v4) | (f2bf(v5) << 16);
    pk.w = f2bf(v6) | (f2bf(v7) << 16);
    return pk;
}

// ---------------------------------------------------------------------------
__global__ void init_col_kernel(const float* __restrict__ nf, float* __restrict__ col) {
    int idx = blockIdx.x * 256 + threadIdx.x;
    int b = idx >> 9, f = idx & 511;
    col[idx] = nf[(b * Nn + Zi) * Ff + f];
}

__global__ void convert_bf16_kernel(const float* __restrict__ src,
                                    unsigned short* __restrict__ dst) {
    int i = blockIdx.x * 256 + threadIdx.x;
    dst[i] = (unsigned short)f2bf(src[i]);
}

// ---------------------------------------------------------------------------
// link L1: C1[(ps*1024 + bc*64 + r), g] = relu(sum_k E[r,k] W1[g,k] + b1[g])
// E[r,k] = x_i[k]*x_j[k].  Block: 256 thr, 4 waves (1M x 4N), tile 64x512,
// K_STEP=32, dbuf reg-staged A/W, transposed [kc][g] LDS planes (pad 32B).
// ---------------------------------------------------------------------------
__global__ __launch_bounds__(256, 2) void link_l1_kernel(
    const float* __restrict__ nf, const float* __restrict__ colp,
    const unsigned short* __restrict__ W1bf, const float* __restrict__ b1,
    unsigned short* __restrict__ C1, int mode, int pair0)
{
    __shared__ char Wb[2][4 * PLW];
    __shared__ char Ab[2][4 * PLA];

    const int tid = threadIdx.x;
    const int ps  = blockIdx.x >> 4;
    const int bc  = blockIdx.x & 15;
    const int p   = pair0 + ps;
    int pi, pj;
    if (mode == 0) { int r = p, i = 0; while (r >= Nn - i) { r -= Nn - i; ++i; } pi = i; pj = i + r; }
    else { pi = p; pj = Zi; }

    const int bloc = tid >> 2;      // row 0..63
    const int kc   = tid & 3;       // k-chunk 0..3
    const int b    = bc * 64 + bloc;
    const float* xi = (pi == Zi) ? (colp + b * Ff) : (nf + (b * Nn + pi) * Ff);
    const float* xj = (pj == Zi) ? (colp + b * Ff) : (nf + (b * Nn + pj) * Ff);

    uint4 wreg[8];
    uint4 areg;

    // ---- stage slice 0 ----
    {
        const float* pxi = xi + kc * 8; const float* pxj = xj + kc * 8;
        float4 u0 = *(const float4*)pxi, u1 = *(const float4*)(pxi + 4);
        float4 v0 = *(const float4*)pxj, v1 = *(const float4*)(pxj + 4);
        areg = pack8(u0.x*v0.x, u0.y*v0.y, u0.z*v0.z, u0.w*v0.w,
                     u1.x*v1.x, u1.y*v1.y, u1.z*v1.z, u1.w*v1.w);
#pragma unroll
        for (int i = 0; i < 8; ++i) {
            int chunk = i * 256 + tid;
            wreg[i] = *(const uint4*)(W1bf + (chunk >> 2) * Ff + (chunk & 3) * 8);
        }
    }
#pragma unroll
    for (int i = 0; i < 8; ++i) {
        int chunk = i * 256 + tid;
        *(uint4*)(&Wb[0][(chunk & 3) * PLW + (chunk >> 2) * 16]) = wreg[i];
    }
    *(uint4*)(&Ab[0][kc * PLA + bloc * 16]) = areg;
    __syncthreads();

    const int l  = tid & 63;
    const int nw = tid >> 6;
    const int lr = l & 31;
    const int kg = l >> 5;

    f32x16 acc[2][4];
#pragma unroll
    for (int m = 0; m < 2; ++m)
#pragma unroll
        for (int n = 0; n < 4; ++n) acc[m][n] = (f32x16)(0.f);

#pragma unroll 1
    for (int ks = 0; ks < 16; ++ks) {
        const int cur = ks & 1;
        if (ks < 15) {
            const int k0 = (ks + 1) * 32;
            const float* pxi = xi + k0 + kc * 8; const float* pxj = xj + k0 + kc * 8;
            float4 u0 = *(const float4*)pxi, u1 = *(const float4*)(pxi + 4);
            float4 v0 = *(const float4*)pxj, v1 = *(const float4*)(pxj + 4);
            areg = pack8(u0.x*v0.x, u0.y*v0.y, u0.z*v0.z, u0.w*v0.w,
                         u1.x*v1.x, u1.y*v1.y, u1.z*v1.z, u1.w*v1.w);
#pragma unroll
            for (int i = 0; i < 8; ++i) {
                int chunk = i * 256 + tid;
                wreg[i] = *(const uint4*)(W1bf + (chunk >> 2) * Ff + k0 + (chunk & 3) * 8);
            }
        }
#pragma unroll
        for (int s = 0; s < 2; ++s) {
            const int kcv = 2 * s + kg;
            bfrag a0 = *(const bfrag*)(&Ab[cur][kcv * PLA + lr * 16]);
            bfrag a1 = *(const bfrag*)(&Ab[cur][kcv * PLA + (32 + lr) * 16]);
#pragma unroll
            for (int nr = 0; nr < 4; ++nr) {
                bfrag bf = *(const bfrag*)(&Wb[cur][kcv * PLW + (nw * 128 + nr * 32 + lr) * 16]);
                acc[0][nr] = __builtin_amdgcn_mfma_f32_32x32x16_bf16(a0, bf, acc[0][nr], 0, 0, 0);
                acc[1][nr] = __builtin_amdgcn_mfma_f32_32x32x16_bf16(a1, bf, acc[1][nr], 0, 0, 0);
            }
        }
        if (ks < 15) {
#pragma unroll
            for (int i = 0; i < 8; ++i) {
                int chunk = i * 256 + tid;
                *(uint4*)(&Wb[cur ^ 1][(chunk & 3) * PLW + (chunk >> 2) * 16]) = wreg[i];
            }
            *(uint4*)(&Ab[cur ^ 1][kc * PLA + bloc * 16]) = areg;
        }
        __syncthreads();
    }

    // ---- epilogue: bias+relu -> bf16 C1 ----
    const int rowbase = ps * 1024 + bc * 64;
#pragma unroll
    for (int nr = 0; nr < 4; ++nr) {
        const int colg = nw * 128 + nr * 32 + lr;
        const float bv = b1[colg];
#pragma unroll
        for (int m = 0; m < 2; ++m) {
#pragma unroll
            for (int reg = 0; reg < 16; ++reg) {
                int row = m * 32 + (reg & 3) + 8 * (reg >> 2) + 4 * kg;
                float v = fmaxf(acc[m][nr][reg] + bv, 0.f);
                C1[(rowbase + row) * Ff + colg] = (unsigned short)f2bf(v);
            }
        }
    }
}

// ---------------------------------------------------------------------------
// link L2: h2 = relu(C1 @ W2^T + b2); adj[b,pi,pj] = h2 . w_out + b_out
// ---------------------------------------------------------------------------
__global__ __launch_bounds__(256, 2) void link_l2_kernel(
    const unsigned short* __restrict__ C1,
    const unsigned short* __restrict__ W2bf, const float* __restrict__ b2,
    const float* __restrict__ w_out, const float* __restrict__ b_out,
    float* __restrict__ adj, int mode, int pair0)
{
    __shared__ char Wb[2][4 * PLW];
    __shared__ char Ab[2][4 * PLA];
    __shared__ float Pl[4][64];

    const int tid = threadIdx.x;
    const int ps  = blockIdx.x >> 4;
    const int bc  = blockIdx.x & 15;
    const int p   = pair0 + ps;
    int pi, pj;
    if (mode == 0) { int r = p, i = 0; while (r >= Nn - i) { r -= Nn - i; ++i; } pi = i; pj = i + r; }
    else { pi = p; pj = Zi; }

    const int bloc = tid >> 2;
    const int kc   = tid & 3;
    const unsigned short* arow = C1 + (ps * 1024 + bc * 64 + bloc) * Ff;

    uint4 wreg[8];
    uint4 areg;

    areg = *(const uint4*)(arow + kc * 8);
#pragma unroll
    for (int i = 0; i < 8; ++i) {
        int chunk = i * 256 + tid;
        wreg[i] = *(const uint4*)(W2bf + (chunk >> 2) * Ff + (chunk & 3) * 8);
    }
#pragma unroll
    for (int i = 0; i < 8; ++i) {
        int chunk = i * 256 + tid;
        *(uint4*)(&Wb[0][(chunk & 3) * PLW + (chunk >> 2) * 16]) = wreg[i];
    }
    *(uint4*)(&Ab[0][kc * PLA + bloc * 16]) = areg;
    __syncthreads();

    const int l  = tid & 63;
    const int nw = tid >> 6;
    const int lr = l & 31;
    const int kg = l >> 5;

    f32x16 acc[2][4];
#pragma unroll
    for (int m = 0; m < 2; ++m)
#pragma unroll
        for (int n = 0; n < 4; ++n) acc[m][n] = (f32x16)(0.f);

#pragma unroll 1
    for (int ks = 0; ks < 16; ++ks) {
        const int cur = ks & 1;
        if (ks < 15) {
            const int k0 = (ks + 1) * 32;
            areg = *(const uint4*)(arow + k0 + kc * 8);
#pragma unroll
            for (int i = 0; i < 8; ++i) {
                int chunk = i * 256 + tid;
                wreg[i] = *(const uint4*)(W2bf + (chunk >> 2) * Ff + k0 + (chunk & 3) * 8);
            }
        }
#pragma unroll
        for (int s = 0; s < 2; ++s) {
            const int kcv = 2 * s + kg;
            bfrag a0 = *(const bfrag*)(&Ab[cur][kcv * PLA + lr * 16]);
            bfrag a1 = *(const bfrag*)(&Ab[cur][kcv * PLA + (32 + lr) * 16]);
#pragma unroll
            for (int nr = 0; nr < 4; ++nr) {
                bfrag bf = *(const bfrag*)(&Wb[cur][kcv * PLW + (nw * 128 + nr * 32 + lr) * 16]);
                acc[0][nr] = __builtin_amdgcn_mfma_f32_32x32x16_bf16(a0, bf, acc[0][nr], 0, 0, 0);
                acc[1][nr] = __builtin_amdgcn_mfma_f32_32x32x16_bf16(a1, bf, acc[1][nr], 0, 0, 0);
            }
        }
        if (ks < 15) {
#pragma unroll
            for (int i = 0; i < 8; ++i) {
                int chunk = i * 256 + tid;
                *(uint4*)(&Wb[cur ^ 1][(chunk & 3) * PLW + (chunk >> 2) * 16]) = wreg[i];
            }
            *(uint4*)(&Ab[cur ^ 1][kc * PLA + bloc * 16]) = areg;
        }
        __syncthreads();
    }

    // ---- epilogue: rowsum of relu(acc+b2)*w_out, butterfly, block-reduce ----
    float rs[2][16];
#pragma unroll
    for (int m = 0; m < 2; ++m)
#pragma unroll
        for (int reg = 0; reg < 16; ++reg) rs[m][reg] = 0.f;
#pragma unroll
    for (int nr = 0; nr < 4; ++nr) {
        const int colg = nw * 128 + nr * 32 + lr;
        const float bv = b2[colg];
        const float wv = w_out[colg];
#pragma unroll
        for (int m = 0; m < 2; ++m)
#pragma unroll
            for (int reg = 0; reg < 16; ++reg)
                rs[m][reg] += fmaxf(acc[m][nr][reg] + bv, 0.f) * wv;
    }
#pragma unroll
    for (int off = 1; off < 32; off <<= 1) {
#pragma unroll
        for (int m = 0; m < 2; ++m)
#pragma unroll
            for (int reg = 0; reg < 16; ++reg)
                rs[m][reg] += __shfl_xor(rs[m][reg], off);
    }
    if (lr == 0) {
#pragma unroll
        for (int m = 0; m < 2; ++m)
#pragma unroll
            for (int reg = 0; reg < 16; ++reg) {
                int row = m * 32 + (reg & 3) + 8 * (reg >> 2) + 4 * kg;
                Pl[nw][row] = rs[m][reg];
            }
    }
    __syncthreads();
    if (tid < 64) {
        float v = b_out[0] + Pl[0][tid] + Pl[1][tid] + Pl[2][tid] + Pl[3][tid];
        int b = bc * 64 + tid;
        adj[b * (Nn * Nn) + pi * Nn + pj] = v;
        if (pi != pj) adj[b * (Nn * Nn) + pj * Nn + pi] = v;
    }
}

// ---------------------------------------------------------------------------
__global__ void softmax_az_kernel(const float* __restrict__ adj, float* __restrict__ a_z) {
    int b = blockIdx.x * 256 + threadIdx.x;
    if (b >= Bsz) return;
    const float* row = adj + b * (Nn * Nn) + Zi * Nn;
    float mx = row[0];
#pragma unroll
    for (int j = 1; j < Nn; ++j) mx = fmaxf(mx, row[j]);
    float e[Nn]; float s = 0.f;
#pragma unroll
    for (int j = 0; j < Nn; ++j) { e[j] = expf(row[j] - mx); s += e[j]; }
    float inv = 1.f / s;
#pragma unroll
    for (int j = 0; j < Nn; ++j) a_z[b * Nn + j] = e[j] * inv;
}

__global__ void mfix_kernel(const float* __restrict__ nf, const float* __restrict__ a_z,
                            float* __restrict__ m_fix) {
    int idx = blockIdx.x * 256 + threadIdx.x;
    int b = idx >> 9, f = idx & 511;
    float s = 0.f;
#pragma unroll
    for (int j = 0; j < Nn - 1; ++j)
        s += a_z[b * Nn + j] * nf[(b * Nn + j) * Ff + f];
    m_fix[idx] = s;
}

// ---------------------------------------------------------------------------
// gates: gi = (m_fix + az*col) @ Wih^T ; gh = col @ Whh^T (fp32 out)
// Block: 256 thr, 4 waves (1M x 4N, Wn=64), tile 64x256, same staging scheme.
// grid (12, 16): xb<6 -> gi (nbase=xb*256), else gh.
// ---------------------------------------------------------------------------
__global__ __launch_bounds__(256, 3) void gates_kernel(
    const float* __restrict__ m_fix, const float* __restrict__ a_z,
    const float* __restrict__ colp,
    const unsigned short* __restrict__ Wih, const unsigned short* __restrict__ Whh,
    float* __restrict__ gi, float* __restrict__ gh)
{
    __shared__ char Wb[2][4 * PGW];
    __shared__ char Ab[2][4 * PLA];

    const int xb = blockIdx.x, bc = blockIdx.y, tid = threadIdx.x;
    const bool isGi = xb < 6;
    const int nbase = (isGi ? xb : xb - 6) * 256;
    const unsigned short* W = isGi ? Wih : Whh;
    float* C = isGi ? gi : gh;

    const int bloc = tid >> 2;
    const int kc   = tid & 3;
    const int b    = bc * 64 + bloc;
    const float* cs = colp + b * Ff;
    const float* mf = m_fix + b * Ff;
    const float azv = isGi ? a_z[b * Nn + Zi] : 0.f;

    uint4 wreg[4];
    uint4 areg;

    auto loadA = [&](int k0) {
        const float* pc = cs + k0 + kc * 8;
        float4 c0 = *(const float4*)pc, c1 = *(const float4*)(pc + 4);
        if (isGi) {
            const float* pm = mf + k0 + kc * 8;
            float4 m0 = *(const float4*)pm, m1 = *(const float4*)(pm + 4);
            areg = pack8(m0.x + azv*c0.x, m0.y + azv*c0.y, m0.z + azv*c0.z, m0.w + azv*c0.w,
                         m1.x + azv*c1.x, m1.y + azv*c1.y, m1.z + azv*c1.z, m1.w + azv*c1.w);
        } else {
            areg = pack8(c0.x, c0.y, c0.z, c0.w, c1.x, c1.y, c1.z, c1.w);
        }
    };

    loadA(0);
#pragma unroll
    for (int i = 0; i < 4; ++i) {
        int chunk = i * 256 + tid;
        wreg[i] = *(const uint4*)(W + (nbase + (chunk >> 2)) * Ff + (chunk & 3) * 8);
    }
#pragma unroll
    for (int i = 0; i < 4; ++i) {
        int chunk = i * 256 + tid;
        *(uint4*)(&Wb[0][(chunk & 3) * PGW + (chunk >> 2) * 16]) = wreg[i];
    }
    *(uint4*)(&Ab[0][kc * PLA + bloc * 16]) = areg;
    __syncthreads();

    const int l  = tid & 63;
    const int nw = tid >> 6;
    const int lr = l & 31;
    const int kg = l >> 5;

    f32x16 acc[2][2];
#pragma unroll
    for (int m = 0; m < 2; ++m)
#pragma unroll
        for (int n = 0; n < 2; ++n) acc[m][n] = (f32x16)(0.f);

#pragma unroll 1
    for (int ks = 0; ks < 16; ++ks) {
        const int cur = ks & 1;
        if (ks < 15) {
            const int k0 = (ks + 1) * 32;
            loadA(k0);
#pragma unroll
            for (int i = 0; i < 4; ++i) {
                int chunk = i * 256 + tid;
                wreg[i] = *(const uint4*)(W + (nbase + (chunk >> 2)) * Ff + k0 + (chunk & 3) * 8);
            }
        }
#pragma unroll
        for (int s = 0; s < 2; ++s) {
            const int kcv = 2 * s + kg;
            bfrag a0 = *(const bfrag*)(&Ab[cur][kcv * PLA + lr * 16]);
            bfrag a1 = *(const bfrag*)(&Ab[cur][kcv * PLA + (32 + lr) * 16]);
#pragma unroll
            for (int nr = 0; nr < 2; ++nr) {
                bfrag bf = *(const bfrag*)(&Wb[cur][kcv * PGW + (nw * 64 + nr * 32 + lr) * 16]);
                acc[0][nr] = __builtin_amdgcn_mfma_f32_32x32x16_bf16(a0, bf, acc[0][nr], 0, 0, 0);
                acc[1][nr] = __builtin_amdgcn_mfma_f32_32x32x16_bf16(a1, bf, acc[1][nr], 0, 0, 0);
            }
        }
        if (ks < 15) {
#pragma unroll
            for (int i = 0; i < 4; ++i) {
                int chunk = i * 256 + tid;
                *(uint4*)(&Wb[cur ^ 1][(chunk & 3) * PGW + (chunk >> 2) * 16]) = wreg[i];
            }
            *(uint4*)(&Ab[cur ^ 1][kc * PLA + bloc * 16]) = areg;
        }
        __syncthreads();
    }

#pragma unroll
    for (int nr = 0; nr < 2; ++nr) {
        const int colg = nbase + nw * 64 + nr * 32 + lr;
#pragma unroll
        for (int m = 0; m < 2; ++m) {
#pragma unroll
            for (int reg = 0; reg < 16; ++reg) {
                int row = m * 32 + (reg & 3) + 8 * (reg >> 2) + 4 * kg;
                C[(bc * 64 + row) * G3 + colg] = acc[m][nr][reg];
            }
        }
    }
}

// ---------------------------------------------------------------------------
__global__ void gru_kernel(const float* __restrict__ gi, const float* __restrict__ gh,
                           float* __restrict__ col) {
    int idx = blockIdx.x * 256 + threadIdx.x;   // 4 f per thread
    int b = idx >> 7, f = (idx & 127) * 4;
    const float* gib = gi + b * G3;
    const float* ghb = gh + b * G3;
    float4 ir = *(const float4*)(gib + f);
    float4 iz = *(const float4*)(gib + Ff + f);
    float4 in = *(const float4*)(gib + 2 * Ff + f);
    float4 hr = *(const float4*)(ghb + f);
    float4 hz = *(const float4*)(ghb + Ff + f);
    float4 hn = *(const float4*)(ghb + 2 * Ff + f);
    float4 h  = *(const float4*)(col + b * Ff + f);
    float4 o;
#define GRU1(c) { \
    float r = 1.f / (1.f + expf(-(ir.c + hr.c))); \
    float z = 1.f / (1.f + expf(-(iz.c + hz.c))); \
    float n = tanhf(in.c + r * hn.c); \
    o.c = (1.f - z) * n + z * h.c; }
    GRU1(x) GRU1(y) GRU1(z) GRU1(w)
#undef GRU1
    *(float4*)(col + b * Ff + f) = o;
}

// ---------------------------------------------------------------------------
extern "C" void kernel_launch(void* const* d_in, const int* in_sizes, int n_in,
                              void* d_out, int out_size, void* d_ws, size_t ws_size,
                              hipStream_t stream) {
    const float* nf    = (const float*)d_in[0];
    const float* W1    = (const float*)d_in[1];
    const float* b1    = (const float*)d_in[2];
    const float* W2    = (const float*)d_in[3];
    const float* b2    = (const float*)d_in[4];
    const float* w_out = (const float*)d_in[5];
    const float* b_out = (const float*)d_in[6];
    const float* W_ih  = (const float*)d_in[7];
    const float* W_hh  = (const float*)d_in[8];

    float* adj = (float*)d_out;                 // (B, 11, 11)
    float* col = adj + Bsz * Nn * Nn;           // (B, 512)

    float* ws    = (float*)d_ws;
    float* a_z   = ws;                          // 16384 floats
    float* m_fix = ws + 16384;                  // B*512
    float* gi    = m_fix + Bsz * Ff;            // B*1536
    float* gh    = gi + Bsz * G3;               // B*1536
    unsigned short* W1bf  = (unsigned short*)(gh + Bsz * G3);
    unsigned short* W2bf  = W1bf + Ff * Ff;
    unsigned short* Wihbf = W2bf + Ff * Ff;
    unsigned short* Whhbf = Wihbf + G3 * Ff;
    // C1 aliases gi+gh (12 MB = exactly 12 pairs x 1024 x 512 bf16). The link
    // phase (L1 writes C1, L2 reads C1) completes before gates touches gi/gh
    // on the same stream, so the reuse is safe and keeps ws footprint at the
    // round-3-validated level.
    unsigned short* C1 = (unsigned short*)gi;
    const int cap = 12;

    init_col_kernel<<<(Bsz * Ff) / 256, 256, 0, stream>>>(nf, col);
    convert_bf16_kernel<<<(Ff * Ff) / 256, 256, 0, stream>>>(W1, W1bf);
    convert_bf16_kernel<<<(Ff * Ff) / 256, 256, 0, stream>>>(W2, W2bf);
    convert_bf16_kernel<<<(G3 * Ff) / 256, 256, 0, stream>>>(W_ih, Wihbf);
    convert_bf16_kernel<<<(G3 * Ff) / 256, 256, 0, stream>>>(W_hh, Whhbf);

    for (int t = 0; t < 3; ++t) {
        const int mode   = (t == 0) ? 0 : 1;
        const int npairs = (t == 0) ? 66 : 11;
        for (int p0 = 0; p0 < npairs; p0 += cap) {
            int np = npairs - p0; if (np > cap) np = cap;
            link_l1_kernel<<<np * 16, 256, 0, stream>>>(nf, col, W1bf, b1, C1, mode, p0);
            link_l2_kernel<<<np * 16, 256, 0, stream>>>(C1, W2bf, b2, w_out, b_out, adj, mode, p0);
        }
        softmax_az_kernel<<<Bsz / 256, 256, 0, stream>>>(adj, a_z);
        mfix_kernel<<<(Bsz * Ff) / 256, 256, 0, stream>>>(nf, a_z, m_fix);

        for (int s = 0; s < 3; ++s) {
            gates_kernel<<<dim3(12, 16), 256, 0, stream>>>(m_fix, a_z, col,
                                                           Wihbf, Whhbf, gi, gh);
            gru_kernel<<<(Bsz * Ff) / 4 / 256, 256, 0, stream>>>(gi, gh, col);
        }
    }
}

// Round 6
// 925.973 us; speedup vs baseline: 1.1648x; 1.1648x over previous
//
#include <hip/hip_runtime.h>
#include <hip/hip_bf16.h>
#include <math.h>

#define Bsz 1024
#define Nn  11
#define Ff  512
#define Zi  10
#define G3  1536

#define PLW  8224   // link W plane stride bytes (512 g * 16B + 32 pad)
#define PLA  1056   // A/E plane stride bytes (64 rows * 16B + 32 pad)
#define PGW2 2080   // gates W plane stride (128 g * 16B + 32 pad)

typedef __attribute__((ext_vector_type(8))) short bfrag;
typedef __attribute__((ext_vector_type(16))) float f32x16;

__device__ __forceinline__ unsigned f2bf(float f) {
    __hip_bfloat16 h = __float2bfloat16(f);
    return (unsigned)*reinterpret_cast<unsigned short*>(&h);
}
__device__ __forceinline__ uint4 pack8(float v0, float v1, float v2, float v3,
                                       float v4, float v5, float v6, float v7) {
    uint4 pk;
    pk.x = f2bf(v0) | (f2bf(v1) << 16);
    pk.y = f2bf(v2) | (f2bf(v3) << 16);
    pk.z = f2bf(v4) | (f2bf(v5) << 16);
    pk.w = f2bf(v6) | (f2bf(v7) << 16);
    return pk;
}

// ---------------------------------------------------------------------------
__global__ void init_col_kernel(const float* __restrict__ nf, float* __restrict__ col) {
    int idx = blockIdx.x * 256 + threadIdx.x;
    int b = idx >> 9, f = idx & 511;
    col[idx] = nf[(b * Nn + Zi) * Ff + f];
}

__global__ void convert_bf16_kernel(const float* __restrict__ src,
                                    unsigned short* __restrict__ dst) {
    int i = blockIdx.x * 256 + threadIdx.x;
    dst[i] = (unsigned short)f2bf(src[i]);
}

// ---------------------------------------------------------------------------
// Fused link MLP. Block = 64 rows (1 pair x 64 batches), 256 thr, 4 waves.
// E (64x512 bf16) resident in LDS transposed planes; overwritten in-place by
// h1 between layers. W slices (512g x 32k) double-buffered, reg-staged.
// Wave tile 64x128 (acc[2][4] of 32x32), mfma_32x32x16. One barrier / K-step.
// adj[b,pi,pj] (and mirror) written by the fused w_out reduction.
// ---------------------------------------------------------------------------
__global__ __launch_bounds__(256, 1) void link_fused_kernel(
    const float* __restrict__ nf, const float* __restrict__ colp,
    const unsigned short* __restrict__ W1bf, const float* __restrict__ b1,
    const unsigned short* __restrict__ W2bf, const float* __restrict__ b2,
    const float* __restrict__ w_out, const float* __restrict__ b_out,
    float* __restrict__ adj, int mode)
{
    __shared__ char Eb[64 * PLA];        // 67,584 B : E / h1 planes
    __shared__ char Wb[2][4 * PLW];      // 65,792 B : W slice dbuf

    const int tid = threadIdx.x;
    const int ps  = blockIdx.x >> 4;
    const int bc  = blockIdx.x & 15;
    int pi, pj;
    if (mode == 0) { int r = ps, i = 0; while (r >= Nn - i) { r -= Nn - i; ++i; } pi = i; pj = i + r; }
    else { pi = ps; pj = Zi; }

    const int bloc = tid >> 2;      // row 0..63
    const int kc   = tid & 3;       // k-chunk 0..3
    const int b    = bc * 64 + bloc;
    const float* xi = (pi == Zi) ? (colp + b * Ff) : (nf + (b * Nn + pi) * Ff);
    const float* xj = (pj == Zi) ? (colp + b * Ff) : (nf + (b * Nn + pj) * Ff);

    uint4 wreg[8];

    // ---- issue W1 slice-0 loads (overlap with E build) ----
#pragma unroll
    for (int i = 0; i < 8; ++i) {
        int chunk = i * 256 + tid;
        wreg[i] = *(const uint4*)(W1bf + (chunk >> 2) * Ff + (chunk & 3) * 8);
    }

    // ---- E build: plane ks*4+kc holds k = ks*32 + kc*8 .. +8 for 64 rows ----
#pragma unroll 4
    for (int ks = 0; ks < 16; ++ks) {
        const int k0 = ks * 32 + kc * 8;
        float4 u0 = *(const float4*)(xi + k0), u1 = *(const float4*)(xi + k0 + 4);
        float4 v0 = *(const float4*)(xj + k0), v1 = *(const float4*)(xj + k0 + 4);
        uint4 pk = pack8(u0.x*v0.x, u0.y*v0.y, u0.z*v0.z, u0.w*v0.w,
                         u1.x*v1.x, u1.y*v1.y, u1.z*v1.z, u1.w*v1.w);
        *(uint4*)(&Eb[(ks * 4 + kc) * PLA + bloc * 16]) = pk;
    }
#pragma unroll
    for (int i = 0; i < 8; ++i) {
        int chunk = i * 256 + tid;
        *(uint4*)(&Wb[0][(chunk & 3) * PLW + (chunk >> 2) * 16]) = wreg[i];
    }
    __syncthreads();

    const int l  = tid & 63;
    const int nw = tid >> 6;      // wave = N-quarter (128 cols)
    const int lr = l & 31;
    const int kg = l >> 5;

    f32x16 acc[2][4];

#pragma unroll 1
    for (int layer = 0; layer < 2; ++layer) {
        const unsigned short* W = layer ? W2bf : W1bf;
#pragma unroll
        for (int m = 0; m < 2; ++m)
#pragma unroll
            for (int n = 0; n < 4; ++n) acc[m][n] = (f32x16)(0.f);

#pragma unroll 1
        for (int ks = 0; ks < 16; ++ks) {
            const int cur = ks & 1;
            if (ks < 15) {
                const int k0 = (ks + 1) * 32;
#pragma unroll
                for (int i = 0; i < 8; ++i) {
                    int chunk = i * 256 + tid;
                    wreg[i] = *(const uint4*)(W + (chunk >> 2) * Ff + k0 + (chunk & 3) * 8);
                }
            }
#pragma unroll
            for (int s = 0; s < 2; ++s) {
                const int kcv = 2 * s + kg;
                const int plane = ks * 4 + kcv;
                bfrag a0 = *(const bfrag*)(&Eb[plane * PLA + lr * 16]);
                bfrag a1 = *(const bfrag*)(&Eb[plane * PLA + (32 + lr) * 16]);
#pragma unroll
                for (int nr = 0; nr < 4; ++nr) {
                    bfrag bf = *(const bfrag*)(&Wb[cur][kcv * PLW + (nw * 128 + nr * 32 + lr) * 16]);
                    acc[0][nr] = __builtin_amdgcn_mfma_f32_32x32x16_bf16(a0, bf, acc[0][nr], 0, 0, 0);
                    acc[1][nr] = __builtin_amdgcn_mfma_f32_32x32x16_bf16(a1, bf, acc[1][nr], 0, 0, 0);
                }
            }
            if (ks < 15) {
#pragma unroll
                for (int i = 0; i < 8; ++i) {
                    int chunk = i * 256 + tid;
                    *(uint4*)(&Wb[cur ^ 1][(chunk & 3) * PLW + (chunk >> 2) * 16]) = wreg[i];
                }
            }
            __syncthreads();
        }

        if (layer == 0) {
            // prefetch W2 slice 0 (hides under h1 epilogue)
#pragma unroll
            for (int i = 0; i < 8; ++i) {
                int chunk = i * 256 + tid;
                wreg[i] = *(const uint4*)(W2bf + (chunk >> 2) * Ff + (chunk & 3) * 8);
            }
            // h1 = relu(acc + b1) -> back into Eb planes (in place)
#pragma unroll
            for (int nr = 0; nr < 4; ++nr) {
                const int colg = nw * 128 + nr * 32 + lr;
                const float bv = b1[colg];
                const int pc  = colg >> 3;
                const int off = (colg & 7) * 2;
#pragma unroll
                for (int m = 0; m < 2; ++m) {
#pragma unroll
                    for (int reg = 0; reg < 16; ++reg) {
                        int row = m * 32 + (reg & 3) + 8 * (reg >> 2) + 4 * kg;
                        float v = fmaxf(acc[m][nr][reg] + bv, 0.f);
                        *(unsigned short*)(&Eb[pc * PLA + row * 16 + off]) = (unsigned short)f2bf(v);
                    }
                }
            }
#pragma unroll
            for (int i = 0; i < 8; ++i) {
                int chunk = i * 256 + tid;
                *(uint4*)(&Wb[0][(chunk & 3) * PLW + (chunk >> 2) * 16]) = wreg[i];
            }
            __syncthreads();
        }
    }

    // ---- fused layer-3: rowsum of relu(acc+b2)*w_out ----
    float rs[2][16];
#pragma unroll
    for (int m = 0; m < 2; ++m)
#pragma unroll
        for (int reg = 0; reg < 16; ++reg) rs[m][reg] = 0.f;
#pragma unroll
    for (int nr = 0; nr < 4; ++nr) {
        const int colg = nw * 128 + nr * 32 + lr;
        const float bv = b2[colg];
        const float wv = w_out[colg];
#pragma unroll
        for (int m = 0; m < 2; ++m)
#pragma unroll
            for (int reg = 0; reg < 16; ++reg)
                rs[m][reg] += fmaxf(acc[m][nr][reg] + bv, 0.f) * wv;
    }
#pragma unroll
    for (int off = 1; off < 32; off <<= 1) {
#pragma unroll
        for (int m = 0; m < 2; ++m)
#pragma unroll
            for (int reg = 0; reg < 16; ++reg)
                rs[m][reg] += __shfl_xor(rs[m][reg], off);
    }
    float* Pl = (float*)&Wb[0][0];   // Wb dead now; reuse as 4x64 partials
    if (lr == 0) {
#pragma unroll
        for (int m = 0; m < 2; ++m)
#pragma unroll
            for (int reg = 0; reg < 16; ++reg) {
                int row = m * 32 + (reg & 3) + 8 * (reg >> 2) + 4 * kg;
                Pl[nw * 64 + row] = rs[m][reg];
            }
    }
    __syncthreads();
    if (tid < 64) {
        float v = b_out[0] + Pl[tid] + Pl[64 + tid] + Pl[128 + tid] + Pl[192 + tid];
        int bb = bc * 64 + tid;
        adj[bb * (Nn * Nn) + pi * Nn + pj] = v;
        if (pi != pj) adj[bb * (Nn * Nn) + pj * Nn + pi] = v;
    }
}

// ---------------------------------------------------------------------------
__global__ void softmax_az_kernel(const float* __restrict__ adj, float* __restrict__ a_z) {
    int b = blockIdx.x * 256 + threadIdx.x;
    if (b >= Bsz) return;
    const float* row = adj + b * (Nn * Nn) + Zi * Nn;
    float mx = row[0];
#pragma unroll
    for (int j = 1; j < Nn; ++j) mx = fmaxf(mx, row[j]);
    float e[Nn]; float s = 0.f;
#pragma unroll
    for (int j = 0; j < Nn; ++j) { e[j] = expf(row[j] - mx); s += e[j]; }
    float inv = 1.f / s;
#pragma unroll
    for (int j = 0; j < Nn; ++j) a_z[b * Nn + j] = e[j] * inv;
}

__global__ void mfix_kernel(const float* __restrict__ nf, const float* __restrict__ a_z,
                            float* __restrict__ m_fix) {
    int idx = blockIdx.x * 256 + threadIdx.x;
    int b = idx >> 9, f = idx & 511;
    float s = 0.f;
#pragma unroll
    for (int j = 0; j < Nn - 1; ++j)
        s += a_z[b * Nn + j] * nf[(b * Nn + j) * Ff + f];
    m_fix[idx] = s;
}

// ---------------------------------------------------------------------------
// gates: gi = (m_fix + az*col) @ Wih^T ; gh = col @ Whh^T (fp32 out)
// Block: 256 thr, 4 waves, tile 64 rows x 128 cols (wave = 64x32, acc[2][1]).
// grid (24, 16): xb<12 -> gi (nbase=xb*128), else gh (nbase=(xb-12)*128).
// ---------------------------------------------------------------------------
__global__ __launch_bounds__(256, 3) void gates_kernel(
    const float* __restrict__ m_fix, const float* __restrict__ a_z,
    const float* __restrict__ colp,
    const unsigned short* __restrict__ Wih, const unsigned short* __restrict__ Whh,
    float* __restrict__ gi, float* __restrict__ gh)
{
    __shared__ char Wb[2][4 * PGW2];   // 16,640 B
    __shared__ char Ab[2][4 * PLA];    //  8,448 B

    const int xb = blockIdx.x, bc = blockIdx.y, tid = threadIdx.x;
    const bool isGi = xb < 12;
    const int nbase = (isGi ? xb : xb - 12) * 128;
    const unsigned short* W = isGi ? Wih : Whh;
    float* C = isGi ? gi : gh;

    const int bloc = tid >> 2;
    const int kc   = tid & 3;
    const int b    = bc * 64 + bloc;
    const float* cs = colp + b * Ff;
    const float* mf = m_fix + b * Ff;
    const float azv = isGi ? a_z[b * Nn + Zi] : 0.f;

    uint4 wreg[2];
    uint4 areg;

    auto loadA = [&](int k0) {
        const float* pc = cs + k0 + kc * 8;
        float4 c0 = *(const float4*)pc, c1 = *(const float4*)(pc + 4);
        if (isGi) {
            const float* pm = mf + k0 + kc * 8;
            float4 m0 = *(const float4*)pm, m1 = *(const float4*)(pm + 4);
            areg = pack8(m0.x + azv*c0.x, m0.y + azv*c0.y, m0.z + azv*c0.z, m0.w + azv*c0.w,
                         m1.x + azv*c1.x, m1.y + azv*c1.y, m1.z + azv*c1.z, m1.w + azv*c1.w);
        } else {
            areg = pack8(c0.x, c0.y, c0.z, c0.w, c1.x, c1.y, c1.z, c1.w);
        }
    };

    loadA(0);
#pragma unroll
    for (int i = 0; i < 2; ++i) {
        int chunk = i * 256 + tid;
        wreg[i] = *(const uint4*)(W + (nbase + (chunk >> 2)) * Ff + (chunk & 3) * 8);
    }
#pragma unroll
    for (int i = 0; i < 2; ++i) {
        int chunk = i * 256 + tid;
        *(uint4*)(&Wb[0][(chunk & 3) * PGW2 + (chunk >> 2) * 16]) = wreg[i];
    }
    *(uint4*)(&Ab[0][kc * PLA + bloc * 16]) = areg;
    __syncthreads();

    const int l  = tid & 63;
    const int nw = tid >> 6;
    const int lr = l & 31;
    const int kg = l >> 5;

    f32x16 acc[2];
    acc[0] = (f32x16)(0.f);
    acc[1] = (f32x16)(0.f);

#pragma unroll 1
    for (int ks = 0; ks < 16; ++ks) {
        const int cur = ks & 1;
        if (ks < 15) {
            const int k0 = (ks + 1) * 32;
            loadA(k0);
#pragma unroll
            for (int i = 0; i < 2; ++i) {
                int chunk = i * 256 + tid;
                wreg[i] = *(const uint4*)(W + (nbase + (chunk >> 2)) * Ff + k0 + (chunk & 3) * 8);
            }
        }
#pragma unroll
        for (int s = 0; s < 2; ++s) {
            const int kcv = 2 * s + kg;
            bfrag a0 = *(const bfrag*)(&Ab[cur][kcv * PLA + lr * 16]);
            bfrag a1 = *(const bfrag*)(&Ab[cur][kcv * PLA + (32 + lr) * 16]);
            bfrag bf = *(const bfrag*)(&Wb[cur][kcv * PGW2 + (nw * 32 + lr) * 16]);
            acc[0] = __builtin_amdgcn_mfma_f32_32x32x16_bf16(a0, bf, acc[0], 0, 0, 0);
            acc[1] = __builtin_amdgcn_mfma_f32_32x32x16_bf16(a1, bf, acc[1], 0, 0, 0);
        }
        if (ks < 15) {
#pragma unroll
            for (int i = 0; i < 2; ++i) {
                int chunk = i * 256 + tid;
                *(uint4*)(&Wb[cur ^ 1][(chunk & 3) * PGW2 + (chunk >> 2) * 16]) = wreg[i];
            }
            *(uint4*)(&Ab[cur ^ 1][kc * PLA + bloc * 16]) = areg;
        }
        __syncthreads();
    }

    const int colg = nbase + nw * 32 + lr;
#pragma unroll
    for (int m = 0; m < 2; ++m) {
#pragma unroll
        for (int reg = 0; reg < 16; ++reg) {
            int row = m * 32 + (reg & 3) + 8 * (reg >> 2) + 4 * kg;
            C[(bc * 64 + row) * G3 + colg] = acc[m][reg];
        }
    }
}

// ---------------------------------------------------------------------------
__global__ void gru_kernel(const float* __restrict__ gi, const float* __restrict__ gh,
                           float* __restrict__ col) {
    int idx = blockIdx.x * 256 + threadIdx.x;   // 4 f per thread
    int b = idx >> 7, f = (idx & 127) * 4;
    const float* gib = gi + b * G3;
    const float* ghb = gh + b * G3;
    float4 ir = *(const float4*)(gib + f);
    float4 iz = *(const float4*)(gib + Ff + f);
    float4 in = *(const float4*)(gib + 2 * Ff + f);
    float4 hr = *(const float4*)(ghb + f);
    float4 hz = *(const float4*)(ghb + Ff + f);
    float4 hn = *(const float4*)(ghb + 2 * Ff + f);
    float4 h  = *(const float4*)(col + b * Ff + f);
    float4 o;
#define GRU1(c) { \
    float r = 1.f / (1.f + expf(-(ir.c + hr.c))); \
    float z = 1.f / (1.f + expf(-(iz.c + hz.c))); \
    float n = tanhf(in.c + r * hn.c); \
    o.c = (1.f - z) * n + z * h.c; }
    GRU1(x) GRU1(y) GRU1(z) GRU1(w)
#undef GRU1
    *(float4*)(col + b * Ff + f) = o;
}

// ---------------------------------------------------------------------------
extern "C" void kernel_launch(void* const* d_in, const int* in_sizes, int n_in,
                              void* d_out, int out_size, void* d_ws, size_t ws_size,
                              hipStream_t stream) {
    const float* nf    = (const float*)d_in[0];
    const float* W1    = (const float*)d_in[1];
    const float* b1    = (const float*)d_in[2];
    const float* W2    = (const float*)d_in[3];
    const float* b2    = (const float*)d_in[4];
    const float* w_out = (const float*)d_in[5];
    const float* b_out = (const float*)d_in[6];
    const float* W_ih  = (const float*)d_in[7];
    const float* W_hh  = (const float*)d_in[8];

    float* adj = (float*)d_out;                 // (B, 11, 11)
    float* col = adj + Bsz * Nn * Nn;           // (B, 512)

    float* ws    = (float*)d_ws;
    float* a_z   = ws;                          // 16384 floats slot
    float* m_fix = ws + 16384;                  // B*512
    float* gi    = m_fix + Bsz * Ff;            // B*1536
    float* gh    = gi + Bsz * G3;               // B*1536
    unsigned short* W1bf  = (unsigned short*)(gh + Bsz * G3);
    unsigned short* W2bf  = W1bf + Ff * Ff;
    unsigned short* Wihbf = W2bf + Ff * Ff;
    unsigned short* Whhbf = Wihbf + G3 * Ff;

    init_col_kernel<<<(Bsz * Ff) / 256, 256, 0, stream>>>(nf, col);
    convert_bf16_kernel<<<(Ff * Ff) / 256, 256, 0, stream>>>(W1, W1bf);
    convert_bf16_kernel<<<(Ff * Ff) / 256, 256, 0, stream>>>(W2, W2bf);
    convert_bf16_kernel<<<(G3 * Ff) / 256, 256, 0, stream>>>(W_ih, Wihbf);
    convert_bf16_kernel<<<(G3 * Ff) / 256, 256, 0, stream>>>(W_hh, Whhbf);

    for (int t = 0; t < 3; ++t) {
        if (t == 0)
            link_fused_kernel<<<66 * 16, 256, 0, stream>>>(nf, col, W1bf, b1, W2bf, b2,
                                                           w_out, b_out, adj, 0);
        else
            link_fused_kernel<<<11 * 16, 256, 0, stream>>>(nf, col, W1bf, b1, W2bf, b2,
                                                           w_out, b_out, adj, 1);
        softmax_az_kernel<<<Bsz / 256, 256, 0, stream>>>(adj, a_z);
        mfix_kernel<<<(Bsz * Ff) / 256, 256, 0, stream>>>(nf, a_z, m_fix);

        for (int s = 0; s < 3; ++s) {
            gates_kernel<<<dim3(24, 16), 256, 0, stream>>>(m_fix, a_z, col,
                                                           Wihbf, Whhbf, gi, gh);
            gru_kernel<<<(Bsz * Ff) / 4 / 256, 256, 0, stream>>>(gi, gh, col);
        }
    }
}

// Round 7
// 645.563 us; speedup vs baseline: 1.6708x; 1.4344x over previous
//
#include <hip/hip_runtime.h>
#include <hip/hip_bf16.h>
#include <math.h>

#define Bsz 1024
#define Nn  11
#define Ff  512
#define Zi  10
#define G3  1536

#define PA   4128   // A plane stride: 256 rows * 16B + 32 pad
#define PW   2080   // W plane stride: 128 cols * 16B + 32 pad
#define PLA  1056   // gates A plane stride (64 rows * 16B + 32 pad)
#define PGW2 2080   // gates W plane stride (128 g * 16B + 32 pad)

typedef __attribute__((ext_vector_type(8))) short bfrag;
typedef __attribute__((ext_vector_type(16))) float f32x16;

__device__ __forceinline__ unsigned f2bf(float f) {
    __hip_bfloat16 h = __float2bfloat16(f);
    return (unsigned)*reinterpret_cast<unsigned short*>(&h);
}
__device__ __forceinline__ uint4 pack8(float v0, float v1, float v2, float v3,
                                       float v4, float v5, float v6, float v7) {
    uint4 pk;
    pk.x = f2bf(v0) | (f2bf(v1) << 16);
    pk.y = f2bf(v2) | (f2bf(v3) << 16);
    pk.z = f2bf(v4) | (f2bf(v5) << 16);
    pk.w = f2bf(v6) | (f2bf(v7) << 16);
    return pk;
}
__device__ __forceinline__ void pair_decode(int mode, int p, int& pi, int& pj) {
    if (mode == 0) { int r = p, i = 0; while (r >= Nn - i) { r -= Nn - i; ++i; } pi = i; pj = i + r; }
    else { pi = p; pj = Zi; }
}

// ---------------------------------------------------------------------------
__global__ void init_col_kernel(const float* __restrict__ nf, float* __restrict__ col) {
    int idx = blockIdx.x * 256 + threadIdx.x;
    int b = idx >> 9, f = idx & 511;
    col[idx] = nf[(b * Nn + Zi) * Ff + f];
}

__global__ void convert_bf16_kernel(const float* __restrict__ src,
                                    unsigned short* __restrict__ dst) {
    int i = blockIdx.x * 256 + threadIdx.x;
    dst[i] = (unsigned short)f2bf(src[i]);
}

// ---------------------------------------------------------------------------
// adj entries for this t's pairs <- b_out (L2 partials atomicAdd on top)
// ---------------------------------------------------------------------------
__global__ void adj_init_kernel(float* __restrict__ adj, const float* __restrict__ b_out,
                                int mode, int npairs) {
    int idx = blockIdx.x * 256 + threadIdx.x;
    if (idx >= Bsz * npairs) return;
    int b = idx / npairs, q = idx - b * npairs;
    int pi, pj; pair_decode(mode, q, pi, pj);
    float v = b_out[0];
    adj[b * (Nn * Nn) + pi * Nn + pj] = v;
    if (pi != pj) adj[b * (Nn * Nn) + pj * Nn + pi] = v;
}

// ---------------------------------------------------------------------------
// link L1: C1[mb*256 + r, col] = relu(sum_k E[r,k] W1[col,k] + b1[col])
// grid (np*4, 4). Block: 512 thr, 8 waves (4M x 2N), tile 256 x 128, K_STEP=32.
// Reg-staged dbuf A (generated E) + W; zero-conflict plane layout.
// ---------------------------------------------------------------------------
__global__ __launch_bounds__(512, 4) void link_l1_kernel(
    const float* __restrict__ nf, const float* __restrict__ colp,
    const unsigned short* __restrict__ W1bf, const float* __restrict__ b1,
    unsigned short* __restrict__ C1, int mode, int pair0)
{
    __shared__ char Ab[2][4 * PA];
    __shared__ char Wb[2][4 * PW];

    const int tid = threadIdx.x;
    const int mb  = blockIdx.x;
    const int nb  = blockIdx.y;
    const int p   = pair0 + (mb >> 2);
    const int b0  = (mb & 3) * 256;
    int pi, pj; pair_decode(mode, p, pi, pj);

    const int ar  = tid >> 1;           // A row 0..255
    const int akc = (tid & 1) * 2;      // kc pair base {0,2}
    const int bb  = b0 + ar;
    const float* xi = (pi == Zi) ? (colp + bb * Ff) : (nf + (bb * Nn + pi) * Ff);
    const float* xj = (pj == Zi) ? (colp + bb * Ff) : (nf + (bb * Nn + pj) * Ff);
    const int wc  = tid >> 2;           // W col 0..127
    const int wkc = tid & 3;
    const unsigned short* wsrc = W1bf + (nb * 128 + wc) * Ff + wkc * 8;

    uint4 wreg, areg0, areg1;

    auto loadAW = [&](int k0) {
        const float* pxi = xi + k0 + akc * 8;
        const float* pxj = xj + k0 + akc * 8;
        float4 u0 = *(const float4*)pxi,       u1 = *(const float4*)(pxi + 4);
        float4 u2 = *(const float4*)(pxi + 8), u3 = *(const float4*)(pxi + 12);
        float4 v0 = *(const float4*)pxj,       v1 = *(const float4*)(pxj + 4);
        float4 v2 = *(const float4*)(pxj + 8), v3 = *(const float4*)(pxj + 12);
        wreg  = *(const uint4*)(wsrc + k0);
        areg0 = pack8(u0.x*v0.x, u0.y*v0.y, u0.z*v0.z, u0.w*v0.w,
                      u1.x*v1.x, u1.y*v1.y, u1.z*v1.z, u1.w*v1.w);
        areg1 = pack8(u2.x*v2.x, u2.y*v2.y, u2.z*v2.z, u2.w*v2.w,
                      u3.x*v3.x, u3.y*v3.y, u3.z*v3.z, u3.w*v3.w);
    };
    auto storeBuf = [&](int buf) {
        *(uint4*)(&Ab[buf][ akc      * PA + ar * 16]) = areg0;
        *(uint4*)(&Ab[buf][(akc + 1) * PA + ar * 16]) = areg1;
        *(uint4*)(&Wb[buf][ wkc      * PW + wc * 16]) = wreg;
    };

    loadAW(0);
    storeBuf(0);
    __syncthreads();

    const int wid = tid >> 6;
    const int Mg  = wid >> 1;     // 0..3 (64-row group)
    const int Ng  = wid & 1;      // 0..1 (64-col group)
    const int l   = tid & 63;
    const int lr  = l & 31;
    const int kg  = l >> 5;

    f32x16 acc[2][2];
#pragma unroll
    for (int m = 0; m < 2; ++m)
#pragma unroll
        for (int n = 0; n < 2; ++n) acc[m][n] = (f32x16)(0.f);

#pragma unroll 1
    for (int ks = 0; ks < 16; ++ks) {
        const int cur = ks & 1;
        if (ks < 15) loadAW((ks + 1) * 32);
#pragma unroll
        for (int s = 0; s < 2; ++s) {
            const int kcv = 2 * s + kg;
            bfrag a0 = *(const bfrag*)(&Ab[cur][kcv * PA + (Mg * 64 + lr) * 16]);
            bfrag a1 = *(const bfrag*)(&Ab[cur][kcv * PA + (Mg * 64 + 32 + lr) * 16]);
            bfrag w0 = *(const bfrag*)(&Wb[cur][kcv * PW + (Ng * 64 + lr) * 16]);
            bfrag w1 = *(const bfrag*)(&Wb[cur][kcv * PW + (Ng * 64 + 32 + lr) * 16]);
            acc[0][0] = __builtin_amdgcn_mfma_f32_32x32x16_bf16(a0, w0, acc[0][0], 0, 0, 0);
            acc[0][1] = __builtin_amdgcn_mfma_f32_32x32x16_bf16(a0, w1, acc[0][1], 0, 0, 0);
            acc[1][0] = __builtin_amdgcn_mfma_f32_32x32x16_bf16(a1, w0, acc[1][0], 0, 0, 0);
            acc[1][1] = __builtin_amdgcn_mfma_f32_32x32x16_bf16(a1, w1, acc[1][1], 0, 0, 0);
        }
        if (ks < 15) storeBuf(cur ^ 1);
        __syncthreads();
    }

    // epilogue: bias + relu -> bf16 C1
#pragma unroll
    for (int ni = 0; ni < 2; ++ni) {
        const int col = nb * 128 + Ng * 64 + ni * 32 + lr;
        const float bv = b1[col];
#pragma unroll
        for (int mi = 0; mi < 2; ++mi) {
#pragma unroll
            for (int reg = 0; reg < 16; ++reg) {
                int row = Mg * 64 + mi * 32 + (reg & 3) + 8 * (reg >> 2) + 4 * kg;
                float v = fmaxf(acc[mi][ni][reg] + bv, 0.f);
                C1[(mb * 256 + row) * Ff + col] = (unsigned short)f2bf(v);
            }
        }
    }
}

// ---------------------------------------------------------------------------
// link L2: partial = sum_cols relu(C1 @ W2^T + b2)*w_out over this nb's 128
// cols; atomicAdd into adj (pre-initialized with b_out).
// ---------------------------------------------------------------------------
__global__ __launch_bounds__(512, 4) void link_l2_kernel(
    const unsigned short* __restrict__ C1,
    const unsigned short* __restrict__ W2bf, const float* __restrict__ b2,
    const float* __restrict__ w_out,
    float* __restrict__ adj, int mode, int pair0)
{
    __shared__ char Ab[2][4 * PA];
    __shared__ char Wb[2][4 * PW];
    __shared__ float Pl[2][256];

    const int tid = threadIdx.x;
    const int mb  = blockIdx.x;
    const int nb  = blockIdx.y;
    const int p   = pair0 + (mb >> 2);
    const int b0  = (mb & 3) * 256;
    int pi, pj; pair_decode(mode, p, pi, pj);

    const int ar  = tid >> 1;
    const int akc = (tid & 1) * 2;
    const unsigned short* c1row = C1 + (mb * 256 + ar) * Ff;
    const int wc  = tid >> 2;
    const int wkc = tid & 3;
    const unsigned short* wsrc = W2bf + (nb * 128 + wc) * Ff + wkc * 8;

    uint4 wreg, areg0, areg1;
    auto loadAW = [&](int k0) {
        areg0 = *(const uint4*)(c1row + k0 + akc * 8);
        areg1 = *(const uint4*)(c1row + k0 + akc * 8 + 8);
        wreg  = *(const uint4*)(wsrc + k0);
    };
    auto storeBuf = [&](int buf) {
        *(uint4*)(&Ab[buf][ akc      * PA + ar * 16]) = areg0;
        *(uint4*)(&Ab[buf][(akc + 1) * PA + ar * 16]) = areg1;
        *(uint4*)(&Wb[buf][ wkc      * PW + wc * 16]) = wreg;
    };

    loadAW(0);
    storeBuf(0);
    __syncthreads();

    const int wid = tid >> 6;
    const int Mg  = wid >> 1;
    const int Ng  = wid & 1;
    const int l   = tid & 63;
    const int lr  = l & 31;
    const int kg  = l >> 5;

    f32x16 acc[2][2];
#pragma unroll
    for (int m = 0; m < 2; ++m)
#pragma unroll
        for (int n = 0; n < 2; ++n) acc[m][n] = (f32x16)(0.f);

#pragma unroll 1
    for (int ks = 0; ks < 16; ++ks) {
        const int cur = ks & 1;
        if (ks < 15) loadAW((ks + 1) * 32);
#pragma unroll
        for (int s = 0; s < 2; ++s) {
            const int kcv = 2 * s + kg;
            bfrag a0 = *(const bfrag*)(&Ab[cur][kcv * PA + (Mg * 64 + lr) * 16]);
            bfrag a1 = *(const bfrag*)(&Ab[cur][kcv * PA + (Mg * 64 + 32 + lr) * 16]);
            bfrag w0 = *(const bfrag*)(&Wb[cur][kcv * PW + (Ng * 64 + lr) * 16]);
            bfrag w1 = *(const bfrag*)(&Wb[cur][kcv * PW + (Ng * 64 + 32 + lr) * 16]);
            acc[0][0] = __builtin_amdgcn_mfma_f32_32x32x16_bf16(a0, w0, acc[0][0], 0, 0, 0);
            acc[0][1] = __builtin_amdgcn_mfma_f32_32x32x16_bf16(a0, w1, acc[0][1], 0, 0, 0);
            acc[1][0] = __builtin_amdgcn_mfma_f32_32x32x16_bf16(a1, w0, acc[1][0], 0, 0, 0);
            acc[1][1] = __builtin_amdgcn_mfma_f32_32x32x16_bf16(a1, w1, acc[1][1], 0, 0, 0);
        }
        if (ks < 15) storeBuf(cur ^ 1);
        __syncthreads();
    }

    // epilogue: relu(acc+b2)*w_out rowsum over this block's 128 cols
    float rs[2][16];
#pragma unroll
    for (int m = 0; m < 2; ++m)
#pragma unroll
        for (int reg = 0; reg < 16; ++reg) rs[m][reg] = 0.f;
#pragma unroll
    for (int ni = 0; ni < 2; ++ni) {
        const int col = nb * 128 + Ng * 64 + ni * 32 + lr;
        const float bv = b2[col];
        const float wv = w_out[col];
#pragma unroll
        for (int mi = 0; mi < 2; ++mi)
#pragma unroll
            for (int reg = 0; reg < 16; ++reg)
                rs[mi][reg] += fmaxf(acc[mi][ni][reg] + bv, 0.f) * wv;
    }
#pragma unroll
    for (int off = 1; off < 32; off <<= 1)
#pragma unroll
        for (int m = 0; m < 2; ++m)
#pragma unroll
            for (int reg = 0; reg < 16; ++reg)
                rs[m][reg] += __shfl_xor(rs[m][reg], off);
    if (lr == 0) {
#pragma unroll
        for (int mi = 0; mi < 2; ++mi)
#pragma unroll
            for (int reg = 0; reg < 16; ++reg) {
                int row = Mg * 64 + mi * 32 + (reg & 3) + 8 * (reg >> 2) + 4 * kg;
                Pl[Ng][row] = rs[mi][reg];
            }
    }
    __syncthreads();
    if (tid < 256) {
        float v = Pl[0][tid] + Pl[1][tid];
        int b = b0 + tid;
        atomicAdd(&adj[b * (Nn * Nn) + pi * Nn + pj], v);
        if (pi != pj) atomicAdd(&adj[b * (Nn * Nn) + pj * Nn + pi], v);
    }
}

// ---------------------------------------------------------------------------
__global__ void softmax_az_kernel(const float* __restrict__ adj, float* __restrict__ a_z) {
    int b = blockIdx.x * 256 + threadIdx.x;
    if (b >= Bsz) return;
    const float* row = adj + b * (Nn * Nn) + Zi * Nn;
    float mx = row[0];
#pragma unroll
    for (int j = 1; j < Nn; ++j) mx = fmaxf(mx, row[j]);
    float e[Nn]; float s = 0.f;
#pragma unroll
    for (int j = 0; j < Nn; ++j) { e[j] = expf(row[j] - mx); s += e[j]; }
    float inv = 1.f / s;
#pragma unroll
    for (int j = 0; j < Nn; ++j) a_z[b * Nn + j] = e[j] * inv;
}

__global__ void mfix_kernel(const float* __restrict__ nf, const float* __restrict__ a_z,
                            float* __restrict__ m_fix) {
    int idx = blockIdx.x * 256 + threadIdx.x;
    int b = idx >> 9, f = idx & 511;
    float s = 0.f;
#pragma unroll
    for (int j = 0; j < Nn - 1; ++j)
        s += a_z[b * Nn + j] * nf[(b * Nn + j) * Ff + f];
    m_fix[idx] = s;
}

// ---------------------------------------------------------------------------
// gates: gi = (m_fix + az*col) @ Wih^T ; gh = col @ Whh^T (fp32 out)
// ---------------------------------------------------------------------------
__global__ __launch_bounds__(256, 3) void gates_kernel(
    const float* __restrict__ m_fix, const float* __restrict__ a_z,
    const float* __restrict__ colp,
    const unsigned short* __restrict__ Wih, const unsigned short* __restrict__ Whh,
    float* __restrict__ gi, float* __restrict__ gh)
{
    __shared__ char Wb[2][4 * PGW2];
    __shared__ char Ab[2][4 * PLA];

    const int xb = blockIdx.x, bc = blockIdx.y, tid = threadIdx.x;
    const bool isGi = xb < 12;
    const int nbase = (isGi ? xb : xb - 12) * 128;
    const unsigned short* W = isGi ? Wih : Whh;
    float* C = isGi ? gi : gh;

    const int bloc = tid >> 2;
    const int kc   = tid & 3;
    const int b    = bc * 64 + bloc;
    const float* cs = colp + b * Ff;
    const float* mf = m_fix + b * Ff;
    const float azv = isGi ? a_z[b * Nn + Zi] : 0.f;

    uint4 wreg[2];
    uint4 areg;

    auto loadA = [&](int k0) {
        const float* pc = cs + k0 + kc * 8;
        float4 c0 = *(const float4*)pc, c1 = *(const float4*)(pc + 4);
        if (isGi) {
            const float* pm = mf + k0 + kc * 8;
            float4 m0 = *(const float4*)pm, m1 = *(const float4*)(pm + 4);
            areg = pack8(m0.x + azv*c0.x, m0.y + azv*c0.y, m0.z + azv*c0.z, m0.w + azv*c0.w,
                         m1.x + azv*c1.x, m1.y + azv*c1.y, m1.z + azv*c1.z, m1.w + azv*c1.w);
        } else {
            areg = pack8(c0.x, c0.y, c0.z, c0.w, c1.x, c1.y, c1.z, c1.w);
        }
    };

    loadA(0);
#pragma unroll
    for (int i = 0; i < 2; ++i) {
        int chunk = i * 256 + tid;
        wreg[i] = *(const uint4*)(W + (nbase + (chunk >> 2)) * Ff + (chunk & 3) * 8);
    }
#pragma unroll
    for (int i = 0; i < 2; ++i) {
        int chunk = i * 256 + tid;
        *(uint4*)(&Wb[0][(chunk & 3) * PGW2 + (chunk >> 2) * 16]) = wreg[i];
    }
    *(uint4*)(&Ab[0][kc * PLA + bloc * 16]) = areg;
    __syncthreads();

    const int l  = tid & 63;
    const int nw = tid >> 6;
    const int lr = l & 31;
    const int kg = l >> 5;

    f32x16 acc[2];
    acc[0] = (f32x16)(0.f);
    acc[1] = (f32x16)(0.f);

#pragma unroll 1
    for (int ks = 0; ks < 16; ++ks) {
        const int cur = ks & 1;
        if (ks < 15) {
            const int k0 = (ks + 1) * 32;
            loadA(k0);
#pragma unroll
            for (int i = 0; i < 2; ++i) {
                int chunk = i * 256 + tid;
                wreg[i] = *(const uint4*)(W + (nbase + (chunk >> 2)) * Ff + k0 + (chunk & 3) * 8);
            }
        }
#pragma unroll
        for (int s = 0; s < 2; ++s) {
            const int kcv = 2 * s + kg;
            bfrag a0 = *(const bfrag*)(&Ab[cur][kcv * PLA + lr * 16]);
            bfrag a1 = *(const bfrag*)(&Ab[cur][kcv * PLA + (32 + lr) * 16]);
            bfrag bf = *(const bfrag*)(&Wb[cur][kcv * PGW2 + (nw * 32 + lr) * 16]);
            acc[0] = __builtin_amdgcn_mfma_f32_32x32x16_bf16(a0, bf, acc[0], 0, 0, 0);
            acc[1] = __builtin_amdgcn_mfma_f32_32x32x16_bf16(a1, bf, acc[1], 0, 0, 0);
        }
        if (ks < 15) {
#pragma unroll
            for (int i = 0; i < 2; ++i) {
                int chunk = i * 256 + tid;
                *(uint4*)(&Wb[cur ^ 1][(chunk & 3) * PGW2 + (chunk >> 2) * 16]) = wreg[i];
            }
            *(uint4*)(&Ab[cur ^ 1][kc * PLA + bloc * 16]) = areg;
        }
        __syncthreads();
    }

    const int colg = nbase + nw * 32 + lr;
#pragma unroll
    for (int m = 0; m < 2; ++m) {
#pragma unroll
        for (int reg = 0; reg < 16; ++reg) {
            int row = m * 32 + (reg & 3) + 8 * (reg >> 2) + 4 * kg;
            C[(bc * 64 + row) * G3 + colg] = acc[m][reg];
        }
    }
}

// ---------------------------------------------------------------------------
__global__ void gru_kernel(const float* __restrict__ gi, const float* __restrict__ gh,
                           float* __restrict__ col) {
    int idx = blockIdx.x * 256 + threadIdx.x;   // 4 f per thread
    int b = idx >> 7, f = (idx & 127) * 4;
    const float* gib = gi + b * G3;
    const float* ghb = gh + b * G3;
    float4 ir = *(const float4*)(gib + f);
    float4 iz = *(const float4*)(gib + Ff + f);
    float4 in = *(const float4*)(gib + 2 * Ff + f);
    float4 hr = *(const float4*)(ghb + f);
    float4 hz = *(const float4*)(ghb + Ff + f);
    float4 hn = *(const float4*)(ghb + 2 * Ff + f);
    float4 h  = *(const float4*)(col + b * Ff + f);
    float4 o;
#define GRU1(c) { \
    float r = 1.f / (1.f + expf(-(ir.c + hr.c))); \
    float z = 1.f / (1.f + expf(-(iz.c + hz.c))); \
    float n = tanhf(in.c + r * hn.c); \
    o.c = (1.f - z) * n + z * h.c; }
    GRU1(x) GRU1(y) GRU1(z) GRU1(w)
#undef GRU1
    *(float4*)(col + b * Ff + f) = o;
}

// ---------------------------------------------------------------------------
extern "C" void kernel_launch(void* const* d_in, const int* in_sizes, int n_in,
                              void* d_out, int out_size, void* d_ws, size_t ws_size,
                              hipStream_t stream) {
    const float* nf    = (const float*)d_in[0];
    const float* W1    = (const float*)d_in[1];
    const float* b1    = (const float*)d_in[2];
    const float* W2    = (const float*)d_in[3];
    const float* b2    = (const float*)d_in[4];
    const float* w_out = (const float*)d_in[5];
    const float* b_out = (const float*)d_in[6];
    const float* W_ih  = (const float*)d_in[7];
    const float* W_hh  = (const float*)d_in[8];

    float* adj = (float*)d_out;                 // (B, 11, 11)
    float* col = adj + Bsz * Nn * Nn;           // (B, 512)

    // ws layout: weights | a_z | m_fix | arena { C1  <->  gi, gh }
    unsigned short* W1bf  = (unsigned short*)d_ws;
    unsigned short* W2bf  = W1bf + Ff * Ff;
    unsigned short* Wihbf = W2bf + Ff * Ff;
    unsigned short* Whhbf = Wihbf + G3 * Ff;
    float* a_z   = (float*)(Whhbf + G3 * Ff);
    float* m_fix = a_z + 16384;
    float* arena = m_fix + Bsz * Ff;
    float* gi    = arena;                       // B*1536 (GRU phase)
    float* gh    = gi + Bsz * G3;
    unsigned short* C1 = (unsigned short*)arena; // link phase (time-disjoint)

    size_t fixedB = (size_t)((char*)arena - (char*)d_ws);
    long long avail = (long long)ws_size - (long long)fixedB;
    int cap = (int)(avail / ((long long)Bsz * Ff * 2));
    if (cap > 66) cap = 66;
    if (cap < 1)  cap = 1;

    init_col_kernel<<<(Bsz * Ff) / 256, 256, 0, stream>>>(nf, col);
    convert_bf16_kernel<<<(Ff * Ff) / 256, 256, 0, stream>>>(W1, W1bf);
    convert_bf16_kernel<<<(Ff * Ff) / 256, 256, 0, stream>>>(W2, W2bf);
    convert_bf16_kernel<<<(G3 * Ff) / 256, 256, 0, stream>>>(W_ih, Wihbf);
    convert_bf16_kernel<<<(G3 * Ff) / 256, 256, 0, stream>>>(W_hh, Whhbf);

    for (int t = 0; t < 3; ++t) {
        const int mode   = (t == 0) ? 0 : 1;
        const int npairs = (t == 0) ? 66 : 11;

        adj_init_kernel<<<(Bsz * npairs + 255) / 256, 256, 0, stream>>>(adj, b_out, mode, npairs);
        for (int p0 = 0; p0 < npairs; p0 += cap) {
            int np = npairs - p0; if (np > cap) np = cap;
            link_l1_kernel<<<dim3(np * 4, 4), 512, 0, stream>>>(nf, col, W1bf, b1, C1, mode, p0);
            link_l2_kernel<<<dim3(np * 4, 4), 512, 0, stream>>>(C1, W2bf, b2, w_out, adj, mode, p0);
        }
        softmax_az_kernel<<<Bsz / 256, 256, 0, stream>>>(adj, a_z);
        mfix_kernel<<<(Bsz * Ff) / 256, 256, 0, stream>>>(nf, a_z, m_fix);

        for (int s = 0; s < 3; ++s) {
            gates_kernel<<<dim3(24, 16), 256, 0, stream>>>(m_fix, a_z, col,
                                                           Wihbf, Whhbf, gi, gh);
            gru_kernel<<<(Bsz * Ff) / 4 / 256, 256, 0, stream>>>(gi, gh, col);
        }
    }
}